// Round 2
// baseline (156.803 us; speedup 1.0000x reference)
//
#include <hip/hip_runtime.h>

#define BSZ 512
#define EPSF 1e-5f

// Distance transform per reference: v = max(sqdist,0); zmask; sqrt(+eps) etc.
__device__ __forceinline__ float dist_xform(float v) {
    v = fmaxf(v, 0.0f);
    float z = (v == 0.0f) ? 1.0f : 0.0f;
    v = sqrtf(v + z * EPSF) + EPSF;
    return v * (1.0f - z);
}

// Per-anchor triplet reduction. drow = distances from anchor a to all j.
__device__ __forceinline__ void triplet_phase(int a, const float* drow,
                                              const int* lab, int* poslist,
                                              int* npos_s, float* wsum, int* wcnt,
                                              float* __restrict__ partial, int tid) {
    if (tid == 0) *npos_s = 0;
    __syncthreads();
    const int la = lab[a];
    for (int t = tid; t < BSZ; t += 256) {
        if (lab[t] == la && t != a) {
            int idx = atomicAdd(npos_s, 1);
            poslist[idx] = t;
        }
    }
    __syncthreads();
    const int npos = *npos_s;
    const int nneg = BSZ - 1 - npos;  // all non-same-label are valid negatives

    float sum = 0.0f;
    int   cnt = 0;
    const int total = npos * BSZ;
    for (int idx = tid; idx < total; idx += 256) {
        const int p = poslist[idx >> 9];   // same p across 512 idx -> LDS broadcast
        const int n = idx & (BSZ - 1);     // consecutive threads -> consecutive banks
        if (lab[n] != la) {
            const float v = drow[p] - drow[n];   // margin = 0
            if (v > 0.0f)  sum += v;
            if (v > 1e-5f) cnt++;
        }
    }
#pragma unroll
    for (int off = 32; off > 0; off >>= 1) {
        sum += __shfl_down(sum, off);
        cnt += __shfl_down(cnt, off);
    }
    const int wave = tid >> 6, lane = tid & 63;
    if (lane == 0) { wsum[wave] = sum; wcnt[wave] = cnt; }
    __syncthreads();
    if (tid == 0) {
        partial[a]           = wsum[0] + wsum[1] + wsum[2] + wsum[3];
        partial[BSZ + a]     = (float)(wcnt[0] + wcnt[1] + wcnt[2] + wcnt[3]);
        partial[2*BSZ + a]   = (float)npos * (float)nneg;
    }
    __syncthreads();   // protect npos_s/poslist reuse for the next anchor
}

// One block per 2 anchors: distances (reg-resident anchor rows) + triplet sums.
__global__ __launch_bounds__(256) void fused_kernel(const float* __restrict__ E,
                                                    const int* __restrict__ labels,
                                                    float* __restrict__ partial) {
    const int tid = threadIdx.x;
    const int g = tid >> 3;          // group 0..31: one j-row per group
    const int l = tid & 7;           // lane in group: contiguous 128B segment
    const int a0 = blockIdx.x;
    const int a1 = blockIdx.x + 256;

    __shared__ float drow0[BSZ];
    __shared__ float drow1[BSZ];
    __shared__ int   lab[BSZ];
    __shared__ int   poslist[BSZ];
    __shared__ int   npos_s;
    __shared__ float wsum[4];
    __shared__ int   wcnt[4];

    for (int t = tid; t < BSZ; t += 256) lab[t] = labels[t];

    // Anchor rows -> registers (16 float4 each). Fixed slice c*8+l per thread.
    const float4* ra0 = (const float4*)(E + (size_t)a0 * BSZ);
    const float4* ra1 = (const float4*)(E + (size_t)a1 * BSZ);
    float4 e0[16], e1[16];
#pragma unroll
    for (int c = 0; c < 16; ++c) { e0[c] = ra0[c * 8 + l]; e1[c] = ra1[c * 8 + l]; }

    // Phase 1: d[a,j] = ||e_a - e_j||, 32 j-rows per pass, 8 lanes per row.
    for (int j0 = 0; j0 < BSZ; j0 += 32) {
        const int j = j0 + g;
        const float4* rj = (const float4*)(E + (size_t)j * BSZ);
        float s0 = 0.0f, s1 = 0.0f;
#pragma unroll
        for (int c = 0; c < 16; ++c) {
            float4 v = rj[c * 8 + l];   // 8 lanes x 16B = contiguous 128B per row
            float d;
            d = e0[c].x - v.x; s0 += d * d;
            d = e0[c].y - v.y; s0 += d * d;
            d = e0[c].z - v.z; s0 += d * d;
            d = e0[c].w - v.w; s0 += d * d;
            d = e1[c].x - v.x; s1 += d * d;
            d = e1[c].y - v.y; s1 += d * d;
            d = e1[c].z - v.z; s1 += d * d;
            d = e1[c].w - v.w; s1 += d * d;
        }
        s0 += __shfl_xor(s0, 4); s0 += __shfl_xor(s0, 2); s0 += __shfl_xor(s0, 1);
        s1 += __shfl_xor(s1, 4); s1 += __shfl_xor(s1, 2); s1 += __shfl_xor(s1, 1);
        if (l == 0) {
            drow0[j] = dist_xform(s0);
            drow1[j] = dist_xform(s1);
        }
    }
    __syncthreads();

    // Phase 2: triplet sums for both anchors.
    triplet_phase(a0, drow0, lab, poslist, &npos_s, wsum, wcnt, partial, tid);
    triplet_phase(a1, drow1, lab, poslist, &npos_s, wsum, wcnt, partial, tid);
}

__global__ __launch_bounds__(256) void final_kernel(const float* __restrict__ partial,
                                                    float* __restrict__ out) {
    const int tid = threadIdx.x;
    float s = partial[tid]         + partial[tid + 256];
    float c = partial[BSZ + tid]   + partial[BSZ + tid + 256];
    float v = partial[2*BSZ + tid] + partial[2*BSZ + tid + 256];
#pragma unroll
    for (int off = 32; off > 0; off >>= 1) {
        s += __shfl_down(s, off);
        c += __shfl_down(c, off);
        v += __shfl_down(v, off);
    }
    __shared__ float ws[4], wc[4], wv[4];
    const int wave = tid >> 6, lane = tid & 63;
    if (lane == 0) { ws[wave] = s; wc[wave] = c; wv[wave] = v; }
    __syncthreads();
    if (tid == 0) {
        float S = ws[0] + ws[1] + ws[2] + ws[3];
        float C = wc[0] + wc[1] + wc[2] + wc[3];
        float V = wv[0] + wv[1] + wv[2] + wv[3];
        out[0] = S / (C + 1e-5f);   // loss
        out[1] = C / (V + 1e-5f);   // fraction_positive
    }
}

extern "C" void kernel_launch(void* const* d_in, const int* in_sizes, int n_in,
                              void* d_out, int out_size, void* d_ws, size_t ws_size,
                              hipStream_t stream) {
    const float* E      = (const float*)d_in[0];   // embeddings [512,512] fp32
    const int*   labels = (const int*)d_in[1];     // labels [512]
    float* out = (float*)d_out;

    float* partial = (float*)d_ws;                 // 3*512 floats

    fused_kernel<<<256, 256, 0, stream>>>(E, labels, partial);
    final_kernel<<<1, 256, 0, stream>>>(partial, out);
}

// Round 3
// 86.160 us; speedup vs baseline: 1.8199x; 1.8199x over previous
//
#include <hip/hip_runtime.h>

#define BSZ 512
#define EPSF 1e-5f
#define TILE 64          // output tile: 64x64
#define KT   32          // k-chunk per block
#define NS   16          // split-k factor (NS*KT = 512)
#define LDST 68          // LDS row stride: 64 + 4 pad (16B aligned, 2-way max conflict)

__device__ __forceinline__ float dist_xform(float v) {
    v = fmaxf(v, 0.0f);
    float z = (v == 0.0f) ? 1.0f : 0.0f;   // zmask per reference
    v = sqrtf(v + z * EPSF) + EPSF;
    return v * (1.0f - z);
}

// ---- Kernel 1: partial squared distances, 64x64 tile, 8x8 micro, split-k ----
// P[s][i][j] = sum_{k in [s*KT,(s+1)*KT)} (E[i,k]-E[j,k])^2
__global__ __launch_bounds__(64) void dsq_kernel(const float* __restrict__ E,
                                                 float* __restrict__ P) {
    __shared__ float As[KT][LDST];   // transposed: As[kk][row]
    __shared__ float Bs[KT][LDST];
    const int tid = threadIdx.x;               // 64 threads = 1 wave
    const int tx = tid & 7, ty = tid >> 3;     // 8x8 thread grid, 8x8 micro-tile
    const int bj = blockIdx.x * TILE;
    const int bi = blockIdx.y * TILE;
    const int k0 = blockIdx.z * KT;

    // Stage both slabs transposed. Coalesced global float4; scalar LDS writes.
    const int lc  = (tid & 7) * 4;   // k offset 0,4,..,28
    const int lr0 = tid >> 3;        // row 0..7
#pragma unroll
    for (int p = 0; p < 8; ++p) {
        const int row = p * 8 + lr0;
        float4 av = *(const float4*)(E + (size_t)(bi + row) * BSZ + k0 + lc);
        float4 bv = *(const float4*)(E + (size_t)(bj + row) * BSZ + k0 + lc);
        As[lc  ][row] = av.x; As[lc+1][row] = av.y; As[lc+2][row] = av.z; As[lc+3][row] = av.w;
        Bs[lc  ][row] = bv.x; Bs[lc+1][row] = bv.y; Bs[lc+2][row] = bv.z; Bs[lc+3][row] = bv.w;
    }
    __syncthreads();

    float acc[8][8];
#pragma unroll
    for (int r = 0; r < 8; ++r)
#pragma unroll
        for (int c = 0; c < 8; ++c) acc[r][c] = 0.0f;

#pragma unroll 4
    for (int kk = 0; kk < KT; ++kk) {
        float4 A0 = *(const float4*)&As[kk][ty * 8];
        float4 A1 = *(const float4*)&As[kk][ty * 8 + 4];
        float4 B0 = *(const float4*)&Bs[kk][tx * 8];
        float4 B1 = *(const float4*)&Bs[kk][tx * 8 + 4];
        float ar[8] = {A0.x, A0.y, A0.z, A0.w, A1.x, A1.y, A1.z, A1.w};
        float br[8] = {B0.x, B0.y, B0.z, B0.w, B1.x, B1.y, B1.z, B1.w};
#pragma unroll
        for (int r = 0; r < 8; ++r)
#pragma unroll
            for (int c = 0; c < 8; ++c) {
                float d = ar[r] - br[c];
                acc[r][c] = fmaf(d, d, acc[r][c]);
            }
    }

    float* Pp = P + (size_t)blockIdx.z * BSZ * BSZ;
#pragma unroll
    for (int r = 0; r < 8; ++r) {
        float4 v0 = {acc[r][0], acc[r][1], acc[r][2], acc[r][3]};
        float4 v1 = {acc[r][4], acc[r][5], acc[r][6], acc[r][7]};
        float* dst = Pp + (size_t)(bi + ty * 8 + r) * BSZ + bj + tx * 8;
        *(float4*)dst       = v0;
        *(float4*)(dst + 4) = v1;
    }
}

// ---- Kernel 2: per-anchor triplet sums (sums split-k partials + xform) ----
__global__ __launch_bounds__(256) void triplet_kernel(const float* __restrict__ P,
                                                      const int* __restrict__ labels,
                                                      float* __restrict__ partial) {
    const int a = blockIdx.x;
    const int tid = threadIdx.x;    // 256 threads
    __shared__ float drow[BSZ];
    __shared__ int   lab[BSZ];
    __shared__ int   poslist[BSZ];
    __shared__ int   npos_s;
    __shared__ float wsum[4];
    __shared__ int   wcnt[4];

    if (tid == 0) npos_s = 0;
    for (int t = tid; t < BSZ; t += 256) lab[t] = labels[t];

    if (tid < 128) {   // 128 threads x float4 = 512 cols
        float4 s4 = {0.f, 0.f, 0.f, 0.f};
#pragma unroll
        for (int s = 0; s < NS; ++s) {
            float4 v = *(const float4*)(P + ((size_t)s * BSZ + a) * BSZ + tid * 4);
            s4.x += v.x; s4.y += v.y; s4.z += v.z; s4.w += v.w;
        }
        drow[tid * 4 + 0] = dist_xform(s4.x);
        drow[tid * 4 + 1] = dist_xform(s4.y);
        drow[tid * 4 + 2] = dist_xform(s4.z);
        drow[tid * 4 + 3] = dist_xform(s4.w);
    }
    __syncthreads();

    const int la = lab[a];
    for (int t = tid; t < BSZ; t += 256) {
        if (lab[t] == la && t != a) {
            int idx = atomicAdd(&npos_s, 1);
            poslist[idx] = t;
        }
    }
    __syncthreads();

    const int npos = npos_s;
    const int nneg = BSZ - 1 - npos;
    float sum = 0.0f;
    int   cnt = 0;
    const int total = npos * BSZ;
    for (int idx = tid; idx < total; idx += 256) {
        const int p = poslist[idx >> 9];   // idx / 512 (same p across a wave -> broadcast)
        const int n = idx & (BSZ - 1);
        if (lab[n] != la) {
            const float v = drow[p] - drow[n];   // margin = 0
            if (v > 0.0f)  sum += v;
            if (v > 1e-5f) cnt++;
        }
    }
#pragma unroll
    for (int off = 32; off > 0; off >>= 1) {
        sum += __shfl_down(sum, off);
        cnt += __shfl_down(cnt, off);
    }
    const int wave = tid >> 6, lane = tid & 63;
    if (lane == 0) { wsum[wave] = sum; wcnt[wave] = cnt; }
    __syncthreads();
    if (tid == 0) {
        partial[a]           = wsum[0] + wsum[1] + wsum[2] + wsum[3];
        partial[BSZ + a]     = (float)(wcnt[0] + wcnt[1] + wcnt[2] + wcnt[3]);
        partial[2*BSZ + a]   = (float)npos * (float)nneg;
    }
}

// ---- Kernel 3: final reduce + scalar epilogue ----
__global__ __launch_bounds__(256) void final_kernel(const float* __restrict__ partial,
                                                    float* __restrict__ out) {
    const int tid = threadIdx.x;
    float s = partial[tid]         + partial[tid + 256];
    float c = partial[BSZ + tid]   + partial[BSZ + tid + 256];
    float v = partial[2*BSZ + tid] + partial[2*BSZ + tid + 256];
#pragma unroll
    for (int off = 32; off > 0; off >>= 1) {
        s += __shfl_down(s, off);
        c += __shfl_down(c, off);
        v += __shfl_down(v, off);
    }
    __shared__ float ws[4], wc[4], wv[4];
    const int wave = tid >> 6, lane = tid & 63;
    if (lane == 0) { ws[wave] = s; wc[wave] = c; wv[wave] = v; }
    __syncthreads();
    if (tid == 0) {
        float S = ws[0] + ws[1] + ws[2] + ws[3];
        float C = wc[0] + wc[1] + wc[2] + wc[3];
        float V = wv[0] + wv[1] + wv[2] + wv[3];
        out[0] = S / (C + 1e-5f);   // loss
        out[1] = C / (V + 1e-5f);   // fraction_positive
    }
}

extern "C" void kernel_launch(void* const* d_in, const int* in_sizes, int n_in,
                              void* d_out, int out_size, void* d_ws, size_t ws_size,
                              hipStream_t stream) {
    const float* E      = (const float*)d_in[0];   // embeddings [512,512] fp32
    const int*   labels = (const int*)d_in[1];     // labels [512]
    float* out = (float*)d_out;

    float* P       = (float*)d_ws;                           // NS * 512 * 512 floats (16 MB)
    float* partial = P + (size_t)NS * BSZ * BSZ;             // 3*512 floats

    dsq_kernel<<<dim3(8, 8, NS), 64, 0, stream>>>(E, P);
    triplet_kernel<<<BSZ, 256, 0, stream>>>(P, labels, partial);
    final_kernel<<<1, 256, 0, stream>>>(partial, out);
}